// Round 1
// baseline (608.362 us; speedup 1.0000x reference)
//
#include <hip/hip_runtime.h>
#include <hip/hip_bf16.h>
#include <stdint.h>

#define B_  4096
#define IN_ 1024
#define H_  2048
#define K_  (IN_ + H_)   // 3072
#define N_  (5 * H_)     // 10240

#define BM 128
#define BN 128
#define BK 32

typedef __attribute__((ext_vector_type(8))) short   short8;
typedef __attribute__((ext_vector_type(4))) float   f32x4;

// ---------- helpers ----------
__device__ __forceinline__ unsigned short f2bf(float f) {
  union { float f; unsigned u; } cv; cv.f = f;
  unsigned u = cv.u;
  u += 0x7fffu + ((u >> 16) & 1u);   // round-to-nearest-even
  return (unsigned short)(u >> 16);
}

__device__ __forceinline__ float bf2f(unsigned short s) {
  union { unsigned u; float f; } cv; cv.u = ((unsigned)s) << 16;
  return cv.f;
}

__device__ __forceinline__ void async16(const unsigned short* g, unsigned short* l) {
  __builtin_amdgcn_global_load_lds(
      (const __attribute__((address_space(1))) unsigned int*)g,
      (__attribute__((address_space(3))) unsigned int*)(void*)l,
      16, 0, 0);
}

// ---------- kernel 1: combined = bf16([x | h_prev])  [B_, K_] ----------
__global__ void build_combined(const float* __restrict__ x,
                               const float* __restrict__ h,
                               unsigned short* __restrict__ out) {
  const int row = blockIdx.x;
  const float4* xr = (const float4*)(x + (size_t)row * IN_);
  const float4* hr = (const float4*)(h + (size_t)row * H_);
  uint2* orow = (uint2*)(out + (size_t)row * K_);
  for (int c = threadIdx.x; c < K_ / 4; c += 256) {
    float4 v = (c < IN_ / 4) ? xr[c] : hr[c - IN_ / 4];
    uint2 p;
    p.x = (unsigned)f2bf(v.x) | ((unsigned)f2bf(v.y) << 16);
    p.y = (unsigned)f2bf(v.z) | ((unsigned)f2bf(v.w) << 16);
    orow[c] = p;
  }
}

// ---------- kernel 2: Wt[n][k] = bf16(W[k][n])  (LDS-tiled transpose) ----------
__global__ void transpose_convert(const float* __restrict__ W,
                                  unsigned short* __restrict__ Wt) {
  __shared__ float tile[64][33];
  const int n0 = blockIdx.x * 32;   // 320 blocks
  const int k0 = blockIdx.y * 64;   // 48 blocks
  const int tx = threadIdx.x;       // 0..31
  const int ty = threadIdx.y;       // 0..7
  #pragma unroll
  for (int kk = ty; kk < 64; kk += 8)
    tile[kk][tx] = W[(size_t)(k0 + kk) * N_ + n0 + tx];
  __syncthreads();
  #pragma unroll
  for (int nn = ty; nn < 32; nn += 8) {
    unsigned lo = f2bf(tile[2 * tx][nn]);
    unsigned hi = f2bf(tile[2 * tx + 1][nn]);
    *(unsigned*)(&Wt[(size_t)(n0 + nn) * K_ + k0 + 2 * tx]) = lo | (hi << 16);
  }
}

// ---------- kernel 3: Z = combined @ Wt^T  (bf16 MFMA, m97 structure) ----------
__global__ __launch_bounds__(256) void gemm_z(
    const unsigned short* __restrict__ A,   // [B_, K_] bf16
    const unsigned short* __restrict__ Bt,  // [N_, K_] bf16
    unsigned short* __restrict__ Z)         // [B_, N_] bf16
{
  __shared__ unsigned short As[BM * BK];   // 8 KB, pad-free (global_load_lds)
  __shared__ unsigned short Bs[BN * BK];   // 8 KB

  const int tid  = threadIdx.x;
  const int wave = tid >> 6;
  const int lane = tid & 63;
  const int quad = lane >> 4;
  const int lr   = lane & 15;

  const int ntiles = N_ / BN;                 // 80
  const int tile_n = blockIdx.x % ntiles;
  const int tile_m = blockIdx.x / ntiles;

  const int wm = (wave >> 1) * 64;
  const int wn = (wave & 1) * 64;

  f32x4 acc[4][4];
  #pragma unroll
  for (int i = 0; i < 4; ++i)
    #pragma unroll
    for (int j = 0; j < 4; ++j)
      acc[i][j] = (f32x4){0.f, 0.f, 0.f, 0.f};

  // staging: each wave stages 32 rows of A-tile and 32 rows of B-tile,
  // two global_load_lds(16B) instructions each (16 rows x 64B = 1 KB per inst)
  const int srow = wave * 32 + (lane >> 2);
  const int scol = (lane & 3) * 8;                    // shorts
  const unsigned short* aP = A  + ((size_t)tile_m * BM + srow) * K_ + scol;
  const unsigned short* bP = Bt + ((size_t)tile_n * BN + srow) * K_ + scol;
  unsigned short* aL0 = &As[(wave * 32)      * BK];
  unsigned short* aL1 = &As[(wave * 32 + 16) * BK];
  unsigned short* bL0 = &Bs[(wave * 32)      * BK];
  unsigned short* bL1 = &Bs[(wave * 32 + 16) * BK];
  const size_t k16 = (size_t)16 * K_;

  for (int k0 = 0; k0 < K_; k0 += BK) {
    async16(aP + k0,       aL0);
    async16(aP + k0 + k16, aL1);
    async16(bP + k0,       bL0);
    async16(bP + k0 + k16, bL1);
    __syncthreads();   // implicit vmcnt(0) drains the LDS-DMA

    short8 af[4], bf[4];
    #pragma unroll
    for (int mi = 0; mi < 4; ++mi)
      af[mi] = *(const short8*)&As[(wm + mi * 16 + lr) * BK + quad * 8];
    #pragma unroll
    for (int ni = 0; ni < 4; ++ni)
      bf[ni] = *(const short8*)&Bs[(wn + ni * 16 + lr) * BK + quad * 8];

    #pragma unroll
    for (int mi = 0; mi < 4; ++mi)
      #pragma unroll
      for (int ni = 0; ni < 4; ++ni)
        acc[mi][ni] = __builtin_amdgcn_mfma_f32_16x16x32_bf16(
            af[mi], bf[ni], acc[mi][ni], 0, 0, 0);

    __syncthreads();
  }

  // epilogue: C/D layout col=lane&15, row=quad*4+reg  (m89-verified)
  const size_t colbase = (size_t)tile_n * BN + wn + lr;
  #pragma unroll
  for (int mi = 0; mi < 4; ++mi) {
    #pragma unroll
    for (int r = 0; r < 4; ++r) {
      const size_t row = (size_t)tile_m * BM + wm + mi * 16 + quad * 4 + r;
      unsigned short* zp = Z + row * N_ + colbase;
      #pragma unroll
      for (int ni = 0; ni < 4; ++ni)
        zp[ni * 16] = f2bf(acc[mi][ni][r]);
    }
  }
}

// ---------- kernel 4: gates + state update ----------
__global__ void epilogue(const unsigned short* __restrict__ Z, // [B_, N_] bf16
                         const float* __restrict__ c_prev,
                         const float* __restrict__ b,
                         float* __restrict__ out) {             // ht | ct
  const int idx = blockIdx.x * blockDim.x + threadIdx.x;  // over B_*H_
  const int r = idx >> 11;          // H_ = 2048
  const int j = idx & (H_ - 1);
  const unsigned short* zr = Z + (size_t)r * N_ + j;

  const float zf = bf2f(zr[0])        + b[j];
  const float zi = bf2f(zr[H_])       + b[j + H_];
  const float zc = bf2f(zr[2 * H_])   + b[j + 2 * H_];
  const float zo = bf2f(zr[3 * H_])   + b[j + 3 * H_];
  const float ze = bf2f(zr[4 * H_])   + b[j + 4 * H_];

  const float ft = 1.f / (1.f + __expf(-zf));
  const float it = 1.f / (1.f + __expf(-zi));
  const float ch = tanhf(zc);
  const float ot = 1.f / (1.f + __expf(-zo));
  const float et = 1.f / (1.f + __expf(-ze));

  const float ct = ft * c_prev[idx] + it * ch;
  const float th = tanhf(ct);
  float ht = ot * th;
  ht = et * __expf(ht) + (1.f - et) * ht;

  out[idx] = ht;
  out[(size_t)B_ * H_ + idx] = ct;
}

// ---------- launcher ----------
extern "C" void kernel_launch(void* const* d_in, const int* in_sizes, int n_in,
                              void* d_out, int out_size, void* d_ws, size_t ws_size,
                              hipStream_t stream) {
  const float* x = (const float*)d_in[0];
  const float* h = (const float*)d_in[1];
  const float* c = (const float*)d_in[2];
  const float* W = (const float*)d_in[3];
  const float* b = (const float*)d_in[4];
  float* out = (float*)d_out;

  char* ws = (char*)d_ws;
  unsigned short* combined = (unsigned short*)ws;                           // 24 MB
  unsigned short* Wt = (unsigned short*)(ws + (size_t)25165824);            // 60 MB
  unsigned short* Z  = (unsigned short*)(ws + (size_t)25165824 + 62914560); // 80 MB

  build_combined<<<B_, 256, 0, stream>>>(x, h, combined);
  transpose_convert<<<dim3(N_ / 32, K_ / 64), dim3(32, 8), 0, stream>>>(W, Wt);
  gemm_z<<<(B_ / BM) * (N_ / BN), 256, 0, stream>>>(combined, Wt, Z);
  epilogue<<<(B_ * H_) / 256, 256, 0, stream>>>(Z, c, b, out);
}

// Round 2
// 583.510 us; speedup vs baseline: 1.0426x; 1.0426x over previous
//
#include <hip/hip_runtime.h>
#include <hip/hip_bf16.h>
#include <stdint.h>

#define B_  4096
#define IN_ 1024
#define H_  2048
#define K_  (IN_ + H_)   // 3072
#define N_  (5 * H_)     // 10240

#define BM 128
#define BN 128
#define BK 32

typedef __attribute__((ext_vector_type(8))) short   short8;
typedef __attribute__((ext_vector_type(4))) float   f32x4;
typedef __attribute__((ext_vector_type(8))) unsigned short ushort8;

// ---------- helpers ----------
__device__ __forceinline__ unsigned short f2bf(float f) {
  union { float f; unsigned u; } cv; cv.f = f;
  unsigned u = cv.u;
  u += 0x7fffu + ((u >> 16) & 1u);   // round-to-nearest-even
  return (unsigned short)(u >> 16);
}

__device__ __forceinline__ float bf2f(unsigned short s) {
  union { unsigned u; float f; } cv; cv.u = ((unsigned)s) << 16;
  return cv.f;
}

__device__ __forceinline__ void async16(const unsigned short* g, unsigned short* l) {
  __builtin_amdgcn_global_load_lds(
      (const __attribute__((address_space(1))) unsigned int*)g,
      (__attribute__((address_space(3))) unsigned int*)(void*)l,
      16, 0, 0);
}

__device__ __forceinline__ float fsig(float x) {
  // sigmoid via v_exp + v_rcp; x=+-inf safe (rcp(inf)=0)
  return __builtin_amdgcn_rcpf(1.f + __expf(-x));
}
__device__ __forceinline__ float ftanh(float x) {
  // tanh = 1 - 2/(e^{2x}+1); robust for large |x| (rcp(inf)=0 -> 1)
  return 1.f - 2.f * __builtin_amdgcn_rcpf(__expf(2.f * x) + 1.f);
}

// ---------- kernel 1: combined = bf16([x | h_prev])  [B_, K_] ----------
__global__ void build_combined(const float* __restrict__ x,
                               const float* __restrict__ h,
                               unsigned short* __restrict__ out) {
  const int row = blockIdx.x;
  const float4* xr = (const float4*)(x + (size_t)row * IN_);
  const float4* hr = (const float4*)(h + (size_t)row * H_);
  uint2* orow = (uint2*)(out + (size_t)row * K_);
  for (int c = threadIdx.x; c < K_ / 4; c += 256) {
    float4 v = (c < IN_ / 4) ? xr[c] : hr[c - IN_ / 4];
    uint2 p;
    p.x = (unsigned)f2bf(v.x) | ((unsigned)f2bf(v.y) << 16);
    p.y = (unsigned)f2bf(v.z) | ((unsigned)f2bf(v.w) << 16);
    orow[c] = p;
  }
}

// ---------- kernel 2: Wt[n][k] = bf16(W[k][n])  (64x64 LDS-tiled) ----------
__global__ __launch_bounds__(256) void transpose_convert(
    const float* __restrict__ W, unsigned short* __restrict__ Wt) {
  __shared__ float tile[64][65];           // pad: column reads conflict-free
  const int n0 = blockIdx.x * 64;          // 160 blocks
  const int k0 = blockIdx.y * 64;          // 48 blocks
  const int t  = threadIdx.x;

  // load 64x64 floats: thread -> (row = t>>2, col4 = i*4 + (t&3)), float4 each
  const int lrow = t >> 2;
  #pragma unroll
  for (int i = 0; i < 4; ++i) {
    const int col4 = i * 4 + (t & 3);
    const float4 v = *(const float4*)&W[(size_t)(k0 + lrow) * N_ + n0 + col4 * 4];
    float* dst = &tile[lrow][col4 * 4];
    dst[0] = v.x; dst[1] = v.y; dst[2] = v.z; dst[3] = v.w;
  }
  __syncthreads();

  // write transposed: 512 chunks of 8 k-shorts (16B); 2 chunks per thread
  #pragma unroll
  for (int i = 0; i < 2; ++i) {
    const int c2 = t + i * 256;
    const int nn = c2 >> 3;
    const int kc = (c2 & 7) * 8;
    ushort8 p;
    #pragma unroll
    for (int u = 0; u < 8; ++u) p[u] = f2bf(tile[kc + u][nn]);
    *(ushort8*)&Wt[(size_t)(n0 + nn) * K_ + k0 + kc] = p;
  }
}

// ---------- kernel 3: Z = combined @ Wt^T  (bf16 MFMA, m97 structure) ----------
// LDS chunk XOR-swizzle: slot s of row r holds k-chunk (s ^ ((r>>1)&3));
// fragment reads then hit all 8 bank-groups per quad (2-way = free, m136).
__global__ __launch_bounds__(256) void gemm_z(
    const unsigned short* __restrict__ A,   // [B_, K_] bf16
    const unsigned short* __restrict__ Bt,  // [N_, K_] bf16
    unsigned short* __restrict__ Z)         // [B_, N_] bf16
{
  __shared__ unsigned short As[BM * BK];   // 8 KB, pad-free (global_load_lds)
  __shared__ unsigned short Bs[BN * BK];   // 8 KB

  const int tid  = threadIdx.x;
  const int wave = tid >> 6;
  const int lane = tid & 63;
  const int quad = lane >> 4;
  const int lr   = lane & 15;

  const int ntiles = N_ / BN;                 // 80
  const int tile_n = blockIdx.x % ntiles;
  const int tile_m = blockIdx.x / ntiles;

  const int wm = (wave >> 1) * 64;
  const int wn = (wave & 1) * 64;

  f32x4 acc[4][4];
  #pragma unroll
  for (int i = 0; i < 4; ++i)
    #pragma unroll
    for (int j = 0; j < 4; ++j)
      acc[i][j] = (f32x4){0.f, 0.f, 0.f, 0.f};

  // staging: swizzled source chunk so LDS slot (lane&3) of row srow holds
  // chunk (lane&3) ^ ((srow>>1)&3);  (srow>>1)&3 == (lane>>3)&3 here.
  const int srow = wave * 32 + (lane >> 2);
  const int scol = (((lane & 3) ^ ((lane >> 3) & 3))) * 8;     // shorts
  const unsigned short* aP = A  + ((size_t)tile_m * BM + srow) * K_ + scol;
  const unsigned short* bP = Bt + ((size_t)tile_n * BN + srow) * K_ + scol;
  unsigned short* aL0 = &As[(wave * 32)      * BK];
  unsigned short* aL1 = &As[(wave * 32 + 16) * BK];
  unsigned short* bL0 = &Bs[(wave * 32)      * BK];
  unsigned short* bL1 = &Bs[(wave * 32 + 16) * BK];
  const size_t k16 = (size_t)16 * K_;

  // fragment read slot: quad ^ ((row>>1)&3); row-part above lr is mult of 16
  const int rslot = (quad ^ ((lr >> 1) & 3)) * 8;              // shorts

  for (int k0 = 0; k0 < K_; k0 += BK) {
    async16(aP + k0,       aL0);
    async16(aP + k0 + k16, aL1);
    async16(bP + k0,       bL0);
    async16(bP + k0 + k16, bL1);
    __syncthreads();   // implicit vmcnt(0) drains the LDS-DMA

    short8 af[4], bf[4];
    #pragma unroll
    for (int mi = 0; mi < 4; ++mi)
      af[mi] = *(const short8*)&As[(wm + mi * 16 + lr) * BK + rslot];
    #pragma unroll
    for (int ni = 0; ni < 4; ++ni)
      bf[ni] = *(const short8*)&Bs[(wn + ni * 16 + lr) * BK + rslot];

    #pragma unroll
    for (int mi = 0; mi < 4; ++mi)
      #pragma unroll
      for (int ni = 0; ni < 4; ++ni)
        acc[mi][ni] = __builtin_amdgcn_mfma_f32_16x16x32_bf16(
            af[mi], bf[ni], acc[mi][ni], 0, 0, 0);

    __syncthreads();
  }

  // epilogue: C/D layout col=lane&15, row=quad*4+reg  (m89-verified)
  const size_t colbase = (size_t)tile_n * BN + wn + lr;
  #pragma unroll
  for (int mi = 0; mi < 4; ++mi) {
    #pragma unroll
    for (int r = 0; r < 4; ++r) {
      const size_t row = (size_t)tile_m * BM + wm + mi * 16 + quad * 4 + r;
      unsigned short* zp = Z + row * N_ + colbase;
      #pragma unroll
      for (int ni = 0; ni < 4; ++ni)
        zp[ni * 16] = f2bf(acc[mi][ni][r]);
    }
  }
}

// ---------- kernel 4: gates + state update (2 elements / thread) ----------
__global__ __launch_bounds__(256) void epilogue(
    const unsigned short* __restrict__ Z, // [B_, N_] bf16
    const float* __restrict__ c_prev,
    const float* __restrict__ b,
    float* __restrict__ out) {            // ht | ct
  const int idx2 = blockIdx.x * 256 + threadIdx.x;   // over B_*H_/2
  const int r  = idx2 >> 10;            // H_/2 = 1024
  const int j  = (idx2 & 1023) * 2;
  const unsigned short* zr = Z + (size_t)r * N_ + j;

  unsigned zg[5];
  float2 bg[5];
  #pragma unroll
  for (int g = 0; g < 5; ++g) {
    zg[g] = *(const unsigned*)(zr + g * H_);
    bg[g] = *(const float2*)(b + g * H_ + j);
  }
  const float2 cp = *(const float2*)(c_prev + (size_t)r * H_ + j);

  float ht[2], ct[2];
  #pragma unroll
  for (int u = 0; u < 2; ++u) {
    const float zf = bf2f((unsigned short)(zg[0] >> (16 * u))) + (u ? bg[0].y : bg[0].x);
    const float zi = bf2f((unsigned short)(zg[1] >> (16 * u))) + (u ? bg[1].y : bg[1].x);
    const float zc = bf2f((unsigned short)(zg[2] >> (16 * u))) + (u ? bg[2].y : bg[2].x);
    const float zo = bf2f((unsigned short)(zg[3] >> (16 * u))) + (u ? bg[3].y : bg[3].x);
    const float ze = bf2f((unsigned short)(zg[4] >> (16 * u))) + (u ? bg[4].y : bg[4].x);

    const float ft = fsig(zf);
    const float it = fsig(zi);
    const float ch = ftanh(zc);
    const float ot = fsig(zo);
    const float et = fsig(ze);

    const float c0 = u ? cp.y : cp.x;
    const float cn = ft * c0 + it * ch;
    const float th = ftanh(cn);
    float hn = ot * th;
    hn = et * __expf(hn) + (1.f - et) * hn;
    ht[u] = hn; ct[u] = cn;
  }

  float2* o1 = (float2*)(out + (size_t)r * H_ + j);
  float2* o2 = (float2*)(out + (size_t)B_ * H_ + (size_t)r * H_ + j);
  *o1 = make_float2(ht[0], ht[1]);
  *o2 = make_float2(ct[0], ct[1]);
}

// ---------- launcher ----------
extern "C" void kernel_launch(void* const* d_in, const int* in_sizes, int n_in,
                              void* d_out, int out_size, void* d_ws, size_t ws_size,
                              hipStream_t stream) {
  const float* x = (const float*)d_in[0];
  const float* h = (const float*)d_in[1];
  const float* c = (const float*)d_in[2];
  const float* W = (const float*)d_in[3];
  const float* b = (const float*)d_in[4];
  float* out = (float*)d_out;

  char* ws = (char*)d_ws;
  unsigned short* combined = (unsigned short*)ws;                           // 24 MB
  unsigned short* Wt = (unsigned short*)(ws + (size_t)25165824);            // 60 MB
  unsigned short* Z  = (unsigned short*)(ws + (size_t)25165824 + 62914560); // 80 MB

  build_combined<<<B_, 256, 0, stream>>>(x, h, combined);
  transpose_convert<<<dim3(N_ / 64, K_ / 64), 256, 0, stream>>>(W, Wt);
  gemm_z<<<(B_ / BM) * (N_ / BN), 256, 0, stream>>>(combined, Wt, Z);
  epilogue<<<(B_ * H_) / 2 / 256, 256, 0, stream>>>(Z, c, b, out);
}

// Round 3
// 565.026 us; speedup vs baseline: 1.0767x; 1.0327x over previous
//
#include <hip/hip_runtime.h>
#include <hip/hip_bf16.h>
#include <stdint.h>

#define B_  4096
#define IN_ 1024
#define H_  2048
#define K_  (IN_ + H_)   // 3072
#define N_  (5 * H_)     // 10240

#define BM 128
#define BJ 32            // per-gate columns per block (5 gates -> 160 B-rows)
#define BK 32

typedef __attribute__((ext_vector_type(8))) short   short8;
typedef __attribute__((ext_vector_type(4))) float   f32x4;
typedef __attribute__((ext_vector_type(8))) unsigned short ushort8;

// ---------- helpers ----------
__device__ __forceinline__ unsigned short f2bf(float f) {
  union { float f; unsigned u; } cv; cv.f = f;
  unsigned u = cv.u;
  u += 0x7fffu + ((u >> 16) & 1u);   // round-to-nearest-even
  return (unsigned short)(u >> 16);
}

__device__ __forceinline__ void async16(const unsigned short* g, unsigned short* l) {
  __builtin_amdgcn_global_load_lds(
      (const __attribute__((address_space(1))) unsigned int*)g,
      (__attribute__((address_space(3))) unsigned int*)(void*)l,
      16, 0, 0);
}

__device__ __forceinline__ float fsig(float x) {
  return __builtin_amdgcn_rcpf(1.f + __expf(-x));   // rcp(inf)=0 -> safe
}
__device__ __forceinline__ float ftanh(float x) {
  return 1.f - 2.f * __builtin_amdgcn_rcpf(__expf(2.f * x) + 1.f);
}

// ---------- kernel 1: combined = bf16([x | h_prev])  [B_, K_] ----------
__global__ void build_combined(const float* __restrict__ x,
                               const float* __restrict__ h,
                               unsigned short* __restrict__ out) {
  const int row = blockIdx.x;
  const float4* xr = (const float4*)(x + (size_t)row * IN_);
  const float4* hr = (const float4*)(h + (size_t)row * H_);
  uint2* orow = (uint2*)(out + (size_t)row * K_);
  for (int c = threadIdx.x; c < K_ / 4; c += 256) {
    float4 v = (c < IN_ / 4) ? xr[c] : hr[c - IN_ / 4];
    uint2 p;
    p.x = (unsigned)f2bf(v.x) | ((unsigned)f2bf(v.y) << 16);
    p.y = (unsigned)f2bf(v.z) | ((unsigned)f2bf(v.w) << 16);
    orow[c] = p;
  }
}

// ---------- kernel 2: Wt[n][k] = bf16(W[k][n])  (64x64 LDS-tiled) ----------
__global__ __launch_bounds__(256) void transpose_convert(
    const float* __restrict__ W, unsigned short* __restrict__ Wt) {
  __shared__ float tile[64][65];
  const int n0 = blockIdx.x * 64;          // 160 blocks
  const int k0 = blockIdx.y * 64;          // 48 blocks
  const int t  = threadIdx.x;

  // read: 16 lanes cover 256 contiguous bytes per k-row; 4 rows per iter
  const int r0 = t >> 4;                   // 0..15
  const int c4 = t & 15;                   // float4 col index
  #pragma unroll
  for (int i = 0; i < 4; ++i) {
    const int kk = i * 16 + r0;
    const float4 v = *(const float4*)&W[(size_t)(k0 + kk) * N_ + n0 + c4 * 4];
    float* dst = &tile[kk][c4 * 4];
    dst[0] = v.x; dst[1] = v.y; dst[2] = v.z; dst[3] = v.w;
  }
  __syncthreads();

  // write transposed: 8 lanes x 16B = 128B contiguous per n-row
  #pragma unroll
  for (int i = 0; i < 2; ++i) {
    const int c2 = t + i * 256;
    const int nn = c2 >> 3;
    const int kc = (c2 & 7) * 8;
    ushort8 p;
    #pragma unroll
    for (int u = 0; u < 8; ++u) p[u] = f2bf(tile[kc + u][nn]);
    *(ushort8*)&Wt[(size_t)(n0 + nn) * K_ + k0 + kc] = p;
  }
}

// ---------- kernel 3: fused GEMM + xLSTM gate epilogue ----------
// Block: 128 rows x 32 j-cols x 5 gates. Wave: 64 rows x 16 cols x 5 gates,
// acc[4][5]. All 5 gates of an output share lane+reg -> in-register epilogue.
__global__ __launch_bounds__(256) void gemm_fused(
    const unsigned short* __restrict__ A,   // [B_, K_] bf16
    const unsigned short* __restrict__ Bt,  // [N_, K_] bf16
    const float* __restrict__ c_prev,       // [B_, H_]
    const float* __restrict__ bias,         // [5*H_]
    float* __restrict__ out)                // ht | ct
{
  __shared__ unsigned short As[BM * BK];        // 8 KB, pad-free (lds-DMA)
  __shared__ unsigned short Bs[5 * BJ * BK];    // 10 KB

  const int tid  = threadIdx.x;
  const int wave = tid >> 6;
  const int lane = tid & 63;
  const int quad = lane >> 4;
  const int lr   = lane & 15;

  const int tile_m = blockIdx.x >> 6;     // 32 m-tiles (m-major: A reuse in L2)
  const int tile_j = blockIdx.x & 63;     // 64 j-tiles
  const int m0 = tile_m * BM;
  const int j0 = tile_j * BJ;

  const int wm = (wave & 1) * 64;         // row half within block
  const int wn = (wave >> 1) * 16;        // col half within j-tile

  f32x4 acc[4][5];
  #pragma unroll
  for (int mi = 0; mi < 4; ++mi)
    #pragma unroll
    for (int g = 0; g < 5; ++g)
      acc[mi][g] = (f32x4){0.f, 0.f, 0.f, 0.f};

  // staging: 16-row chunks, 64B/row; XOR chunk swizzle so slot (lane&3) of
  // row r holds chunk (lane&3)^((r>>1)&3)  ((r>>1)&3 == (lane>>3)&3, since
  // all chunk row-bases are multiples of 16)
  const int lrow4 = lane >> 2;                                  // 0..15
  const int scol  = ((lane & 3) ^ ((lane >> 3) & 3)) * 8;       // shorts
  const unsigned short* aBase = A  + ((size_t)(m0 + lrow4)) * K_ + scol;
  const unsigned short* bBase = Bt + ((size_t)(j0 + lrow4)) * K_ + scol;
  const size_t k16 = (size_t)16 * K_;

  // fragment read slot: quad ^ ((lr>>1)&3)  (row base parts are mult of 16)
  const int rslot = (quad ^ ((lr >> 1) & 3)) * 8;               // shorts

  for (int k0 = 0; k0 < K_; k0 += BK) {
    // A: 8 chunks of 16 rows; wave stages its own 32 rows (2 insts)
    async16(aBase + (size_t)(wave * 32) * K_ + k0,      &As[(wave * 32) * BK]);
    async16(aBase + (size_t)(wave * 32) * K_ + k16 + k0,&As[(wave * 32 + 16) * BK]);
    // B: 10 chunks (5 gates x 2); chunk c -> gate c>>1, half c&1
    for (int c = wave; c < 10; c += 4) {
      const size_t roff = (size_t)((c >> 1) * H_ + (c & 1) * 16) * K_;
      async16(bBase + roff + k0, &Bs[(c * 16) * BK]);
    }
    __syncthreads();   // implicit vmcnt(0) drains LDS-DMA

    short8 af[4], bf[5];
    #pragma unroll
    for (int mi = 0; mi < 4; ++mi)
      af[mi] = *(const short8*)&As[(wm + mi * 16 + lr) * BK + rslot];
    #pragma unroll
    for (int g = 0; g < 5; ++g)
      bf[g] = *(const short8*)&Bs[(g * 32 + wn + lr) * BK + rslot];

    #pragma unroll
    for (int mi = 0; mi < 4; ++mi)
      #pragma unroll
      for (int g = 0; g < 5; ++g)
        acc[mi][g] = __builtin_amdgcn_mfma_f32_16x16x32_bf16(
            af[mi], bf[g], acc[mi][g], 0, 0, 0);

    __syncthreads();
  }

  // ---- fused epilogue: all 5 gates in-lane, fp32 throughout ----
  const int col = j0 + wn + lr;                    // 0..H_-1
  float bb[5];
  #pragma unroll
  for (int g = 0; g < 5; ++g) bb[g] = bias[g * H_ + col];

  #pragma unroll
  for (int mi = 0; mi < 4; ++mi) {
    float cp[4];
    #pragma unroll
    for (int r = 0; r < 4; ++r)
      cp[r] = c_prev[(size_t)(m0 + wm + mi * 16 + quad * 4 + r) * H_ + col];
    #pragma unroll
    for (int r = 0; r < 4; ++r) {
      const int row = m0 + wm + mi * 16 + quad * 4 + r;
      const float ft = fsig(acc[mi][0][r] + bb[0]);
      const float it = fsig(acc[mi][1][r] + bb[1]);
      const float ch = ftanh(acc[mi][2][r] + bb[2]);
      const float ot = fsig(acc[mi][3][r] + bb[3]);
      const float et = fsig(acc[mi][4][r] + bb[4]);
      const float ct = ft * cp[r] + it * ch;
      const float th = ftanh(ct);
      float ht = ot * th;
      ht = et * __expf(ht) + (1.f - et) * ht;
      out[(size_t)row * H_ + col] = ht;
      out[(size_t)B_ * H_ + (size_t)row * H_ + col] = ct;
    }
  }
}

// ---------- launcher ----------
extern "C" void kernel_launch(void* const* d_in, const int* in_sizes, int n_in,
                              void* d_out, int out_size, void* d_ws, size_t ws_size,
                              hipStream_t stream) {
  const float* x = (const float*)d_in[0];
  const float* h = (const float*)d_in[1];
  const float* c = (const float*)d_in[2];
  const float* W = (const float*)d_in[3];
  const float* b = (const float*)d_in[4];
  float* out = (float*)d_out;

  char* ws = (char*)d_ws;
  unsigned short* combined = (unsigned short*)ws;                  // 24 MB
  unsigned short* Wt = (unsigned short*)(ws + (size_t)25165824);   // 60 MB

  build_combined<<<B_, 256, 0, stream>>>(x, h, combined);
  transpose_convert<<<dim3(N_ / 64, K_ / 64), 256, 0, stream>>>(W, Wt);
  gemm_fused<<<(B_ / BM) * (H_ / BJ), 256, 0, stream>>>(combined, Wt, c, b, out);
}

// Round 4
// 527.994 us; speedup vs baseline: 1.1522x; 1.0701x over previous
//
#include <hip/hip_runtime.h>
#include <hip/hip_bf16.h>
#include <stdint.h>

#define B_  4096
#define IN_ 1024
#define H_  2048
#define K_  (IN_ + H_)   // 3072
#define N_  (5 * H_)     // 10240

#define BM 128
#define BJ 32            // per-gate columns per block (5 gates -> 160 B-rows)
#define BK 32

typedef __attribute__((ext_vector_type(8))) short   short8;
typedef __attribute__((ext_vector_type(4))) float   f32x4;
typedef __attribute__((ext_vector_type(8))) unsigned short ushort8;

// ---------- helpers ----------
__device__ __forceinline__ unsigned short f2bf(float f) {
  union { float f; unsigned u; } cv; cv.f = f;
  unsigned u = cv.u;
  u += 0x7fffu + ((u >> 16) & 1u);   // round-to-nearest-even
  return (unsigned short)(u >> 16);
}

__device__ __forceinline__ void async16(const unsigned short* g, unsigned short* l) {
  __builtin_amdgcn_global_load_lds(
      (const __attribute__((address_space(1))) unsigned int*)g,
      (__attribute__((address_space(3))) unsigned int*)(void*)l,
      16, 0, 0);
}

__device__ __forceinline__ float fsig(float x) {
  return __builtin_amdgcn_rcpf(1.f + __expf(-x));   // rcp(inf)=0 -> safe
}
__device__ __forceinline__ float ftanh(float x) {
  return 1.f - 2.f * __builtin_amdgcn_rcpf(__expf(2.f * x) + 1.f);
}

// ---------- kernel 1: combined = bf16([x | h_prev])  [B_, K_] ----------
__global__ void build_combined(const float* __restrict__ x,
                               const float* __restrict__ h,
                               unsigned short* __restrict__ out) {
  const int row = blockIdx.x;
  const float4* xr = (const float4*)(x + (size_t)row * IN_);
  const float4* hr = (const float4*)(h + (size_t)row * H_);
  uint2* orow = (uint2*)(out + (size_t)row * K_);
  for (int c = threadIdx.x; c < K_ / 4; c += 256) {
    float4 v = (c < IN_ / 4) ? xr[c] : hr[c - IN_ / 4];
    uint2 p;
    p.x = (unsigned)f2bf(v.x) | ((unsigned)f2bf(v.y) << 16);
    p.y = (unsigned)f2bf(v.z) | ((unsigned)f2bf(v.w) << 16);
    orow[c] = p;
  }
}

// ---------- kernel 2: Wt[n][k] = bf16(W[k][n])  (64x64 LDS-tiled) ----------
__global__ __launch_bounds__(256) void transpose_convert(
    const float* __restrict__ W, unsigned short* __restrict__ Wt) {
  __shared__ float tile[64][65];
  const int n0 = blockIdx.x * 64;          // 160 blocks
  const int k0 = blockIdx.y * 64;          // 48 blocks
  const int t  = threadIdx.x;

  const int r0 = t >> 4;                   // 0..15
  const int c4 = t & 15;                   // float4 col index
  #pragma unroll
  for (int i = 0; i < 4; ++i) {
    const int kk = i * 16 + r0;
    const float4 v = *(const float4*)&W[(size_t)(k0 + kk) * N_ + n0 + c4 * 4];
    float* dst = &tile[kk][c4 * 4];
    dst[0] = v.x; dst[1] = v.y; dst[2] = v.z; dst[3] = v.w;
  }
  __syncthreads();

  #pragma unroll
  for (int i = 0; i < 2; ++i) {
    const int c2 = t + i * 256;
    const int nn = c2 >> 3;
    const int kc = (c2 & 7) * 8;
    ushort8 p;
    #pragma unroll
    for (int u = 0; u < 8; ++u) p[u] = f2bf(tile[kc + u][nn]);
    *(ushort8*)&Wt[(size_t)(n0 + nn) * K_ + k0 + kc] = p;
  }
}

// ---------- kernel 3: fused GEMM + xLSTM gate epilogue ----------
// Block: 128 rows x 32 j-cols x 5 gates. Wave: 64 rows x 16 cols x 5 gates,
// acc[4][5]. All 5 gates of an output share lane+reg -> in-register epilogue.
// __launch_bounds__(256,3): cap total VGPR at ~170 so 3 waves/SIMD stay
// resident (R3 post-mortem: 184 regs -> 2 waves/SIMD -> MfmaUtil 30%).
__global__ __launch_bounds__(256, 3) void gemm_fused(
    const unsigned short* __restrict__ A,   // [B_, K_] bf16
    const unsigned short* __restrict__ Bt,  // [N_, K_] bf16
    const float* __restrict__ c_prev,       // [B_, H_]
    const float* __restrict__ bias,         // [5*H_]
    float* __restrict__ out)                // ht | ct
{
  __shared__ unsigned short As[BM * BK];        // 8 KB, pad-free (lds-DMA)
  __shared__ unsigned short Bs[5 * BJ * BK];    // 10 KB

  const int tid  = threadIdx.x;
  const int wave = tid >> 6;
  const int lane = tid & 63;
  const int quad = lane >> 4;
  const int lr   = lane & 15;

  const int tile_m = blockIdx.x >> 6;     // 32 m-tiles
  const int tile_j = blockIdx.x & 63;     // 64 j-tiles
  const int m0 = tile_m * BM;
  const int j0 = tile_j * BJ;

  const int wm = (wave & 1) * 64;         // row half within block
  const int wn = (wave >> 1) * 16;        // col half within j-tile

  f32x4 acc[4][5];
  #pragma unroll
  for (int mi = 0; mi < 4; ++mi)
    #pragma unroll
    for (int g = 0; g < 5; ++g)
      acc[mi][g] = (f32x4){0.f, 0.f, 0.f, 0.f};

  // staging: 16-row chunks of 64B rows; XOR chunk swizzle so LDS slot
  // (lane&3) of row r holds chunk (lane&3)^((r>>1)&3); (r>>1)&3==(lane>>3)&3
  // because every chunk's row base is a multiple of 16.
  const int lrow4 = lane >> 2;                                  // 0..15
  const int scol  = ((lane & 3) ^ ((lane >> 3) & 3)) * 8;       // shorts
  const size_t k16 = (size_t)16 * K_;

  // A: wave stages its own 32 rows (2 chunks)
  const unsigned short* aP =
      A + ((size_t)(m0 + wave * 32 + lrow4)) * K_ + scol;
  unsigned short* aL0 = &As[(wave * 32) * BK];
  unsigned short* aL1 = &As[(wave * 32 + 16) * BK];

  // B: chunk c (0..9) -> gate c>>1, half c&1; wave w owns {2w, 2w+1},
  // waves 0/1 additionally own {8, 9}.  Wave-uniform, fully precomputed.
  const unsigned short* bBase = Bt + ((size_t)(j0 + lrow4)) * K_ + scol;
  const unsigned short* bP0 = bBase + (size_t)wave * H_ * K_;      // c=2w
  const unsigned short* bP2 = bBase + ((size_t)4 * H_ + wave * 16) * K_; // c=8+w
  unsigned short* bL0 = &Bs[(wave * 32) * BK];
  unsigned short* bL1 = &Bs[(wave * 32 + 16) * BK];
  unsigned short* bL2 = &Bs[((8 + wave) * 16) * BK];
  const bool doTail = (wave < 2);

  // fragment read slot: quad ^ ((lr>>1)&3) (row bases are multiples of 16)
  const int rslot = (quad ^ ((lr >> 1) & 3)) * 8;               // shorts

  for (int k0 = 0; k0 < K_; k0 += BK) {
    async16(aP + k0,        aL0);
    async16(aP + k16 + k0,  aL1);
    async16(bP0 + k0,       bL0);
    async16(bP0 + k16 + k0, bL1);
    if (doTail) async16(bP2 + k0, bL2);
    __syncthreads();   // implicit vmcnt(0) drains LDS-DMA

    short8 af[4], bf[5];
    #pragma unroll
    for (int mi = 0; mi < 4; ++mi)
      af[mi] = *(const short8*)&As[(wm + mi * 16 + lr) * BK + rslot];
    #pragma unroll
    for (int g = 0; g < 5; ++g)
      bf[g] = *(const short8*)&Bs[(g * 32 + wn + lr) * BK + rslot];

    #pragma unroll
    for (int mi = 0; mi < 4; ++mi)
      #pragma unroll
      for (int g = 0; g < 5; ++g)
        acc[mi][g] = __builtin_amdgcn_mfma_f32_16x16x32_bf16(
            af[mi], bf[g], acc[mi][g], 0, 0, 0);

    __syncthreads();
  }

  // ---- fused epilogue: all 5 gates in-lane, fp32 throughout ----
  const int col = j0 + wn + lr;                    // 0..H_-1
  float bb[5];
  #pragma unroll
  for (int g = 0; g < 5; ++g) bb[g] = bias[g * H_ + col];

  #pragma unroll
  for (int mi = 0; mi < 4; ++mi) {
    const int rbase = m0 + wm + mi * 16 + quad * 4;
    float cp[4];
    #pragma unroll
    for (int r = 0; r < 4; ++r)
      cp[r] = c_prev[(size_t)(rbase + r) * H_ + col];
    #pragma unroll
    for (int r = 0; r < 4; ++r) {
      const float ft = fsig(acc[mi][0][r] + bb[0]);
      const float it = fsig(acc[mi][1][r] + bb[1]);
      const float ch = ftanh(acc[mi][2][r] + bb[2]);
      const float ot = fsig(acc[mi][3][r] + bb[3]);
      const float et = fsig(acc[mi][4][r] + bb[4]);
      const float ct = ft * cp[r] + it * ch;
      const float th = ftanh(ct);
      float ht = ot * th;
      ht = et * __expf(ht) + (1.f - et) * ht;
      out[(size_t)(rbase + r) * H_ + col] = ht;
      out[(size_t)B_ * H_ + (size_t)(rbase + r) * H_ + col] = ct;
    }
  }
}

// ---------- launcher ----------
extern "C" void kernel_launch(void* const* d_in, const int* in_sizes, int n_in,
                              void* d_out, int out_size, void* d_ws, size_t ws_size,
                              hipStream_t stream) {
  const float* x = (const float*)d_in[0];
  const float* h = (const float*)d_in[1];
  const float* c = (const float*)d_in[2];
  const float* W = (const float*)d_in[3];
  const float* b = (const float*)d_in[4];
  float* out = (float*)d_out;

  char* ws = (char*)d_ws;
  unsigned short* combined = (unsigned short*)ws;                  // 24 MB
  unsigned short* Wt = (unsigned short*)(ws + (size_t)25165824);   // 60 MB

  build_combined<<<B_, 256, 0, stream>>>(x, h, combined);
  transpose_convert<<<dim3(N_ / 64, K_ / 64), 256, 0, stream>>>(W, Wt);
  gemm_fused<<<(B_ / BM) * (H_ / BJ), 256, 0, stream>>>(combined, Wt, c, b, out);
}